// Round 1
// baseline (389.843 us; speedup 1.0000x reference)
//
#include <hip/hip_runtime.h>

using u16 = unsigned short;
typedef __attribute__((ext_vector_type(8))) __bf16 bf16x8;
typedef __attribute__((ext_vector_type(4))) float f32x4;
typedef __attribute__((ext_vector_type(4))) unsigned int u32x4;

__device__ inline u16 f2bf(float f) {
    unsigned u = __float_as_uint(f);
    u += 0x7FFFu + ((u >> 16) & 1u);   // RNE
    return (u16)(u >> 16);
}
__device__ inline unsigned pack2(float a, float b) {
    return (unsigned)f2bf(a) | ((unsigned)f2bf(b) << 16);
}
__device__ inline bf16x8 as_bf16x8(u32x4 v) {
    union { u32x4 u; bf16x8 b; } x; x.u = v; return x.b;
}

// ---------------- transpose + cast fp32 -> bf16 (for W^T) ----------------
// in: [R][C] fp32, out: [C][R] bf16. grid (R/64, C/64), 256 thr.
__global__ __launch_bounds__(256) void tcast_f32(const float* __restrict__ in,
                                                 u16* __restrict__ out,
                                                 int R, int C) {
    __shared__ float tile[64][65];
    const int r0 = blockIdx.x * 64, c0 = blockIdx.y * 64;
    const int t = threadIdx.x;
    {
        const int r = t >> 2, cq = (t & 3) * 16;
        const float* src = in + (size_t)(r0 + r) * C + c0 + cq;
#pragma unroll
        for (int j = 0; j < 4; ++j) {
            f32x4 v = *(const f32x4*)(src + j * 4);
#pragma unroll
            for (int e = 0; e < 4; ++e) tile[r][cq + j * 4 + e] = v[e];
        }
    }
    __syncthreads();
    {
        const int c = t >> 2, rq = (t & 3) * 16;
        u32x4 w0, w1;
#pragma unroll
        for (int j = 0; j < 4; ++j) {
            w0[j] = pack2(tile[rq + 2 * j][c], tile[rq + 2 * j + 1][c]);
            w1[j] = pack2(tile[rq + 8 + 2 * j][c], tile[rq + 8 + 2 * j + 1][c]);
        }
        u16* dst = out + (size_t)(c0 + c) * R + r0 + rq;
        *(u32x4*)dst = w0;
        *(u32x4*)(dst + 8) = w1;
    }
}

// ---------------- batched transpose bf16: V [BH][T][64] -> Vt [BH][64][T] ----
// grid (T/64, BH), 256 thr.
__global__ __launch_bounds__(256) void tv_bf16(const u16* __restrict__ V,
                                               u16* __restrict__ Vt) {
    __shared__ u16 tile[64][68];
    const int t0 = blockIdx.x * 64, bh = blockIdx.y;
    const int t = threadIdx.x;
    {
        const int r = t >> 2, cq = (t & 3) * 16;
        const u16* src = V + ((size_t)bh * 2048 + t0 + r) * 64 + cq;
        u32x4 a = *(const u32x4*)src;
        u32x4 b = *(const u32x4*)(src + 8);
#pragma unroll
        for (int j = 0; j < 4; ++j) {
            tile[r][cq + 2 * j] = (u16)(a[j] & 0xFFFFu);
            tile[r][cq + 2 * j + 1] = (u16)(a[j] >> 16);
            tile[r][cq + 8 + 2 * j] = (u16)(b[j] & 0xFFFFu);
            tile[r][cq + 8 + 2 * j + 1] = (u16)(b[j] >> 16);
        }
    }
    __syncthreads();
    {
        const int d = t >> 2, rq = (t & 3) * 16;
        u32x4 w0, w1;
#pragma unroll
        for (int j = 0; j < 4; ++j) {
            w0[j] = (unsigned)tile[rq + 2 * j][d] | ((unsigned)tile[rq + 2 * j + 1][d] << 16);
            w1[j] = (unsigned)tile[rq + 8 + 2 * j][d] | ((unsigned)tile[rq + 8 + 2 * j + 1][d] << 16);
        }
        u16* dst = Vt + ((size_t)bh * 64 + d) * 2048 + t0 + rq;
        *(u32x4*)dst = w0;
        *(u32x4*)(dst + 8) = w1;
    }
}

// ---------------- GEMM: A [M][K] (fp32 or bf16) x Bt [N][K] bf16 + bias -----
// 128x128 tile, BK=32, 256 thr (4 waves, 2x2 of 64x64), 16x16x32 MFMA.
// EPI 0: QKV routing -> out = u16* base of Q ([B,H,T,64] x3 sections)
// EPI 1: fp32 store out[row*N+col]
template <int EPI, typename TA>
__global__ __launch_bounds__(256) void gemm_kernel(const TA* __restrict__ A,
                                                   const u16* __restrict__ Bt,
                                                   const float* __restrict__ bias,
                                                   void* __restrict__ outp,
                                                   const int M, const int N, const int K) {
    __shared__ char lds[16384];
    char* As = lds;
    char* Bs = lds + 8192;
    const int t = threadIdx.x;
    const int l = t & 63, wid = t >> 6;
    const int wr = wid >> 1, wc = wid & 1;
    const int g = l >> 4, lr = l & 15;
    const int m0 = blockIdx.x * 128, n0 = blockIdx.y * 128;

    f32x4 acc[4][4];
#pragma unroll
    for (int i = 0; i < 4; ++i)
#pragma unroll
        for (int j = 0; j < 4; ++j)
#pragma unroll
            for (int e = 0; e < 4; ++e) acc[i][j][e] = 0.f;

    const int srow = t >> 2;       // 0..63
    const int sk = (t & 3) * 8;    // 0,8,16,24

    for (int k0 = 0; k0 < K; k0 += 32) {
#pragma unroll
        for (int j = 0; j < 2; ++j) {
            const int row = srow + j * 64;
            u32x4 w;
            const TA* src = A + (size_t)(m0 + row) * K + k0 + sk;
            if constexpr (sizeof(TA) == 2) {
                w = *(const u32x4*)src;
            } else {
                f32x4 p0 = *(const f32x4*)src;
                f32x4 p1 = *(const f32x4*)(src + 4);
                w[0] = pack2(p0[0], p0[1]); w[1] = pack2(p0[2], p0[3]);
                w[2] = pack2(p1[0], p1[1]); w[3] = pack2(p1[2], p1[3]);
            }
            *(u32x4*)(As + row * 64 + sk * 2) = w;
            const u16* srcb = Bt + (size_t)(n0 + row) * K + k0 + sk;
            *(u32x4*)(Bs + row * 64 + sk * 2) = *(const u32x4*)srcb;
        }
        __syncthreads();
        bf16x8 a[4], b[4];
#pragma unroll
        for (int m = 0; m < 4; ++m) {
            const int row = wr * 64 + m * 16 + lr;
            a[m] = as_bf16x8(*(const u32x4*)(As + row * 64 + g * 16));
        }
#pragma unroll
        for (int n = 0; n < 4; ++n) {
            const int row = wc * 64 + n * 16 + lr;
            b[n] = as_bf16x8(*(const u32x4*)(Bs + row * 64 + g * 16));
        }
#pragma unroll
        for (int m = 0; m < 4; ++m)
#pragma unroll
            for (int n = 0; n < 4; ++n)
                acc[m][n] = __builtin_amdgcn_mfma_f32_16x16x32_bf16(a[m], b[n], acc[m][n], 0, 0, 0);
        __syncthreads();
    }

#pragma unroll
    for (int m = 0; m < 4; ++m) {
#pragma unroll
        for (int n = 0; n < 4; ++n) {
            const int colg = n0 + wc * 64 + n * 16 + lr;
            const float bv = bias[colg];
#pragma unroll
            for (int r = 0; r < 4; ++r) {
                const int rowg = m0 + wr * 64 + m * 16 + g * 4 + r;
                const float v = acc[m][n][r] + bv;
                if constexpr (EPI == 0) {
                    const int sec = colg >> 10, c = colg & 1023;
                    const int hh = c >> 6, dd = c & 63;
                    const int bb = rowg >> 11, tt = rowg & 2047;
                    u16* dst = (u16*)outp;
                    dst[(size_t)sec * 8388608u +
                        (((size_t)(bb * 16 + hh) * 2048 + tt) << 6) + dd] = f2bf(v);
                } else {
                    ((float*)outp)[(size_t)rowg * N + colg] = v;
                }
            }
        }
    }
}

// ---------------- fused causal flash attention -----------------------------
// grid (T/64, BH), 256 thr. Wave w owns q rows q0+w*16 .. +15. KV tile = 64.
__global__ __launch_bounds__(256) void attn_kernel(const u16* __restrict__ Q,
                                                   const u16* __restrict__ K,
                                                   const u16* __restrict__ Vt,
                                                   u16* __restrict__ Y) {
    __shared__ char lds[24576];          // Ks 8K | Vs 8K | P 4x2K
    char* Ks = lds;
    char* Vs = lds + 8192;
    const int t = threadIdx.x;
    const int l = t & 63, w = t >> 6;
    char* Pw = lds + 16384 + w * 2048;
    const int g = l >> 4, lr = l & 15;
    const int q0 = blockIdx.x * 64, bh = blockIdx.y;

    const u16* Qb = Q + (size_t)bh * (2048 * 64);
    const u16* Kb = K + (size_t)bh * (2048 * 64);
    const u16* Vb = Vt + (size_t)bh * (64 * 2048);

    bf16x8 aq[2];
    {
        const u16* qp = Qb + (size_t)(q0 + w * 16 + lr) * 64 + g * 8;
        aq[0] = as_bf16x8(*(const u32x4*)qp);
        aq[1] = as_bf16x8(*(const u32x4*)(qp + 32));
    }
    f32x4 o[4];
    float mrow[4], lsum[4];
#pragma unroll
    for (int n = 0; n < 4; ++n)
#pragma unroll
        for (int e = 0; e < 4; ++e) o[n][e] = 0.f;
#pragma unroll
    for (int r = 0; r < 4; ++r) { mrow[r] = -3.0e38f; lsum[r] = 0.f; }

    const int row_lo = q0 + w * 16;
    const int ntile = (q0 >> 6) + 1;
    for (int it = 0; it < ntile; ++it) {
        const int kv0 = it << 6;
        {   // stage K tile [64 kv][64 d] and Vt tile [64 d][64 kv], swizzled
            const int r = t >> 2, c0 = (t & 3) * 16;
            const unsigned swz = (unsigned)((r & 7) << 4);
            const unsigned base = (unsigned)(r * 128 + c0 * 2);
            const u16* ksrc = Kb + (size_t)(kv0 + r) * 64 + c0;
            u32x4 ka = *(const u32x4*)ksrc;
            u32x4 kb2 = *(const u32x4*)(ksrc + 8);
            *(u32x4*)(Ks + (base ^ swz)) = ka;
            *(u32x4*)(Ks + ((base + 16) ^ swz)) = kb2;
            const u16* vsrc = Vb + (size_t)r * 2048 + kv0 + c0;
            u32x4 va = *(const u32x4*)vsrc;
            u32x4 vb2 = *(const u32x4*)(vsrc + 8);
            *(u32x4*)(Vs + (base ^ swz)) = va;
            *(u32x4*)(Vs + ((base + 16) ^ swz)) = vb2;
        }
        __syncthreads();
        if (kv0 <= row_lo + 15) {
            f32x4 s[4];
#pragma unroll
            for (int n = 0; n < 4; ++n) {
                f32x4 z; z[0] = z[1] = z[2] = z[3] = 0.f;
#pragma unroll
                for (int kk = 0; kk < 2; ++kk) {
                    const int krow = n * 16 + lr;
                    const unsigned off = (unsigned)(krow * 128 + kk * 64 + g * 16) ^
                                         (unsigned)((krow & 7) << 4);
                    z = __builtin_amdgcn_mfma_f32_16x16x32_bf16(
                        aq[kk], as_bf16x8(*(const u32x4*)(Ks + off)), z, 0, 0, 0);
                }
                s[n] = z;
            }
            float mt[4], al[4], sm[4];
#pragma unroll
            for (int r = 0; r < 4; ++r) mt[r] = -3.0e38f;
#pragma unroll
            for (int n = 0; n < 4; ++n) {
                const int cg = kv0 + n * 16 + lr;
#pragma unroll
                for (int r = 0; r < 4; ++r) {
                    float v = s[n][r] * 0.125f;
                    v = (cg <= row_lo + g * 4 + r) ? v : -3.0e38f;
                    s[n][r] = v;
                    mt[r] = fmaxf(mt[r], v);
                }
            }
#pragma unroll
            for (int off = 1; off < 16; off <<= 1)
#pragma unroll
                for (int r = 0; r < 4; ++r) mt[r] = fmaxf(mt[r], __shfl_xor(mt[r], off));
#pragma unroll
            for (int r = 0; r < 4; ++r) {
                const float mn = fmaxf(mrow[r], mt[r]);
                al[r] = exp2f((mrow[r] - mn) * 1.44269504f);
                mrow[r] = mn;
                sm[r] = 0.f;
            }
#pragma unroll
            for (int n = 0; n < 4; ++n)
#pragma unroll
                for (int r = 0; r < 4; ++r) {
                    const float p = exp2f((s[n][r] - mrow[r]) * 1.44269504f);
                    s[n][r] = p;
                    sm[r] += p;
                }
#pragma unroll
            for (int off = 1; off < 16; off <<= 1)
#pragma unroll
                for (int r = 0; r < 4; ++r) sm[r] += __shfl_xor(sm[r], off);
#pragma unroll
            for (int r = 0; r < 4; ++r) lsum[r] = lsum[r] * al[r] + sm[r];
#pragma unroll
            for (int n = 0; n < 4; ++n)
#pragma unroll
                for (int r = 0; r < 4; ++r) o[n][r] *= al[r];
            // P -> per-wave LDS (swizzled [16][64])
#pragma unroll
            for (int n = 0; n < 4; ++n)
#pragma unroll
                for (int r = 0; r < 4; ++r) {
                    const int prow = g * 4 + r;
                    const unsigned off = (unsigned)(prow * 128 + (n * 16 + lr) * 2) ^
                                         (unsigned)((prow & 7) << 4);
                    *(u16*)(Pw + off) = f2bf(s[n][r]);
                }
            bf16x8 ap[2];
#pragma unroll
            for (int kk = 0; kk < 2; ++kk) {
                const unsigned off = (unsigned)(lr * 128 + kk * 64 + g * 16) ^
                                     (unsigned)((lr & 7) << 4);
                ap[kk] = as_bf16x8(*(const u32x4*)(Pw + off));
            }
#pragma unroll
            for (int n = 0; n < 4; ++n)
#pragma unroll
                for (int kk = 0; kk < 2; ++kk) {
                    const int vrow = n * 16 + lr;
                    const unsigned off = (unsigned)(vrow * 128 + kk * 64 + g * 16) ^
                                         (unsigned)((vrow & 7) << 4);
                    o[n] = __builtin_amdgcn_mfma_f32_16x16x32_bf16(
                        ap[kk], as_bf16x8(*(const u32x4*)(Vs + off)), o[n], 0, 0, 0);
                }
        }
        __syncthreads();
    }
    const int bb = bh >> 4, hh = bh & 15;
#pragma unroll
    for (int r = 0; r < 4; ++r) {
        const int tg = row_lo + g * 4 + r;
        const float inv = 1.f / lsum[r];
#pragma unroll
        for (int n = 0; n < 4; ++n)
            Y[((size_t)(bb * 2048 + tg)) * 1024 + hh * 64 + n * 16 + lr] =
                f2bf(o[n][r] * inv);
    }
}

// ---------------------------------------------------------------------------
extern "C" void kernel_launch(void* const* d_in, const int* in_sizes, int n_in,
                              void* d_out, int out_size, void* d_ws, size_t ws_size,
                              hipStream_t stream) {
    const float* x = (const float*)d_in[0];
    const float* Wqkv = (const float*)d_in[1];
    const float* bqkv = (const float*)d_in[2];
    const float* Wproj = (const float*)d_in[3];
    const float* bproj = (const float*)d_in[4];
    float* out = (float*)d_out;
    char* ws = (char*)d_ws;

    u16* Wtq = (u16*)(ws + 0);            // 3072x1024 bf16  (6.29 MB)
    u16* Wtp = (u16*)(ws + 6291456);      // 1024x1024 bf16  (2.10 MB)
    u16* Qb  = (u16*)(ws + 8388608);      // [B,H,T,64] bf16 (16.78 MB)
    // K at Qb + 8388608 elems, V at Qb + 16777216 elems (contiguous sections)
    u16* Vb  = (u16*)(ws + 41943040);
    u16* Vtb = (u16*)(ws + 58720256);     // [B,H,64,T] bf16
    u16* Yb  = Vb;                        // alias: V dead after transpose

    tcast_f32<<<dim3(16, 48), 256, 0, stream>>>(Wqkv, Wtq, 1024, 3072);
    tcast_f32<<<dim3(16, 16), 256, 0, stream>>>(Wproj, Wtp, 1024, 1024);
    gemm_kernel<0, float><<<dim3(64, 24), 256, 0, stream>>>(
        x, Wtq, bqkv, (void*)Qb, 8192, 3072, 1024);
    tv_bf16<<<dim3(32, 64), 256, 0, stream>>>(Vb, Vtb);
    attn_kernel<<<dim3(32, 64), 256, 0, stream>>>(
        Qb, Qb + 8388608, Vtb, Yb);
    gemm_kernel<1, u16><<<dim3(64, 8), 256, 0, stream>>>(
        Yb, Wtp, bproj, (void*)out, 8192, 1024, 1024);
}

// Round 2
// 387.847 us; speedup vs baseline: 1.0051x; 1.0051x over previous
//
#include <hip/hip_runtime.h>

using u16 = unsigned short;
typedef __attribute__((ext_vector_type(8))) __bf16 bf16x8;
typedef __attribute__((ext_vector_type(4))) float f32x4;
typedef __attribute__((ext_vector_type(4))) unsigned int u32x4;

__device__ inline u16 f2bf(float f) {
    unsigned u = __float_as_uint(f);
    u += 0x7FFFu + ((u >> 16) & 1u);   // RNE
    return (u16)(u >> 16);
}
__device__ inline unsigned pack2(float a, float b) {
    return (unsigned)f2bf(a) | ((unsigned)f2bf(b) << 16);
}
__device__ inline bf16x8 as_bf16x8(u32x4 v) {
    union { u32x4 u; bf16x8 b; } x; x.u = v; return x.b;
}

// ---------------- transpose + cast fp32 -> bf16 (for W^T) ----------------
// in: [R][C] fp32, out: [C][R] bf16. grid (R/64, C/64), 256 thr.
__global__ __launch_bounds__(256) void tcast_f32(const float* __restrict__ in,
                                                 u16* __restrict__ out,
                                                 int R, int C) {
    __shared__ float tile[64][65];
    const int r0 = blockIdx.x * 64, c0 = blockIdx.y * 64;
    const int t = threadIdx.x;
    {
        const int r = t >> 2, cq = (t & 3) * 16;
        const float* src = in + (size_t)(r0 + r) * C + c0 + cq;
#pragma unroll
        for (int j = 0; j < 4; ++j) {
            f32x4 v = *(const f32x4*)(src + j * 4);
#pragma unroll
            for (int e = 0; e < 4; ++e) tile[r][cq + j * 4 + e] = v[e];
        }
    }
    __syncthreads();
    {
        const int c = t >> 2, rq = (t & 3) * 16;
        u32x4 w0, w1;
#pragma unroll
        for (int j = 0; j < 4; ++j) {
            w0[j] = pack2(tile[rq + 2 * j][c], tile[rq + 2 * j + 1][c]);
            w1[j] = pack2(tile[rq + 8 + 2 * j][c], tile[rq + 8 + 2 * j + 1][c]);
        }
        u16* dst = out + (size_t)(c0 + c) * R + r0 + rq;
        *(u32x4*)dst = w0;
        *(u32x4*)(dst + 8) = w1;
    }
}

// ---------------- batched transpose bf16: V [BH][T][64] -> Vt [BH][64][T] ----
// grid (T/64, BH), 256 thr.
__global__ __launch_bounds__(256) void tv_bf16(const u16* __restrict__ V,
                                               u16* __restrict__ Vt) {
    __shared__ u16 tile[64][68];
    const int t0 = blockIdx.x * 64, bh = blockIdx.y;
    const int t = threadIdx.x;
    {
        const int r = t >> 2, cq = (t & 3) * 16;
        const u16* src = V + ((size_t)bh * 2048 + t0 + r) * 64 + cq;
        u32x4 a = *(const u32x4*)src;
        u32x4 b = *(const u32x4*)(src + 8);
#pragma unroll
        for (int j = 0; j < 4; ++j) {
            tile[r][cq + 2 * j] = (u16)(a[j] & 0xFFFFu);
            tile[r][cq + 2 * j + 1] = (u16)(a[j] >> 16);
            tile[r][cq + 8 + 2 * j] = (u16)(b[j] & 0xFFFFu);
            tile[r][cq + 8 + 2 * j + 1] = (u16)(b[j] >> 16);
        }
    }
    __syncthreads();
    {
        const int d = t >> 2, rq = (t & 3) * 16;
        u32x4 w0, w1;
#pragma unroll
        for (int j = 0; j < 4; ++j) {
            w0[j] = (unsigned)tile[rq + 2 * j][d] | ((unsigned)tile[rq + 2 * j + 1][d] << 16);
            w1[j] = (unsigned)tile[rq + 8 + 2 * j][d] | ((unsigned)tile[rq + 8 + 2 * j + 1][d] << 16);
        }
        u16* dst = Vt + ((size_t)bh * 64 + d) * 2048 + t0 + rq;
        *(u32x4*)dst = w0;
        *(u32x4*)(dst + 8) = w1;
    }
}

// ---------------- GEMM: A [M][K] (fp32 or bf16) x Bt [N][K] bf16 + bias -----
// 128x128 tile, BK=32, 256 thr (4 waves, 2x2 of 64x64), 16x16x32 MFMA.
// EPI 0: QKV routing -> out = u16* base of Q ([B,H,T,64] x3 sections)
// EPI 1: fp32 store out[row*N+col]
template <int EPI, typename TA>
__global__ __launch_bounds__(256) void gemm_kernel(const TA* __restrict__ A,
                                                   const u16* __restrict__ Bt,
                                                   const float* __restrict__ bias,
                                                   void* __restrict__ outp,
                                                   const int M, const int N, const int K) {
    __shared__ char lds[16384];
    char* As = lds;
    char* Bs = lds + 8192;
    const int t = threadIdx.x;
    const int l = t & 63, wid = t >> 6;
    const int wr = wid >> 1, wc = wid & 1;
    const int g = l >> 4, lr = l & 15;
    const int m0 = blockIdx.x * 128, n0 = blockIdx.y * 128;

    f32x4 acc[4][4];
#pragma unroll
    for (int i = 0; i < 4; ++i)
#pragma unroll
        for (int j = 0; j < 4; ++j)
#pragma unroll
            for (int e = 0; e < 4; ++e) acc[i][j][e] = 0.f;

    const int srow = t >> 2;       // 0..63
    const int sk = (t & 3) * 8;    // 0,8,16,24

    for (int k0 = 0; k0 < K; k0 += 32) {
#pragma unroll
        for (int j = 0; j < 2; ++j) {
            const int row = srow + j * 64;
            u32x4 w;
            const TA* src = A + (size_t)(m0 + row) * K + k0 + sk;
            if constexpr (sizeof(TA) == 2) {
                w = *(const u32x4*)src;
            } else {
                f32x4 p0 = *(const f32x4*)src;
                f32x4 p1 = *(const f32x4*)(src + 4);
                w[0] = pack2(p0[0], p0[1]); w[1] = pack2(p0[2], p0[3]);
                w[2] = pack2(p1[0], p1[1]); w[3] = pack2(p1[2], p1[3]);
            }
            *(u32x4*)(As + row * 64 + sk * 2) = w;
            const u16* srcb = Bt + (size_t)(n0 + row) * K + k0 + sk;
            *(u32x4*)(Bs + row * 64 + sk * 2) = *(const u32x4*)srcb;
        }
        __syncthreads();
        bf16x8 a[4], b[4];
#pragma unroll
        for (int m = 0; m < 4; ++m) {
            const int row = wr * 64 + m * 16 + lr;
            a[m] = as_bf16x8(*(const u32x4*)(As + row * 64 + g * 16));
        }
#pragma unroll
        for (int n = 0; n < 4; ++n) {
            const int row = wc * 64 + n * 16 + lr;
            b[n] = as_bf16x8(*(const u32x4*)(Bs + row * 64 + g * 16));
        }
#pragma unroll
        for (int m = 0; m < 4; ++m)
#pragma unroll
            for (int n = 0; n < 4; ++n)
                acc[m][n] = __builtin_amdgcn_mfma_f32_16x16x32_bf16(a[m], b[n], acc[m][n], 0, 0, 0);
        __syncthreads();
    }

#pragma unroll
    for (int m = 0; m < 4; ++m) {
#pragma unroll
        for (int n = 0; n < 4; ++n) {
            const int colg = n0 + wc * 64 + n * 16 + lr;
            const float bv = bias[colg];
#pragma unroll
            for (int r = 0; r < 4; ++r) {
                const int rowg = m0 + wr * 64 + m * 16 + g * 4 + r;
                const float v = acc[m][n][r] + bv;
                if constexpr (EPI == 0) {
                    const int sec = colg >> 10, c = colg & 1023;
                    const int hh = c >> 6, dd = c & 63;
                    const int bb = rowg >> 11, tt = rowg & 2047;
                    u16* dst = (u16*)outp;
                    dst[(size_t)sec * 8388608u +
                        (((size_t)(bb * 16 + hh) * 2048 + tt) << 6) + dd] = f2bf(v);
                } else {
                    ((float*)outp)[(size_t)rowg * N + colg] = v;
                }
            }
        }
    }
}

// ---------------- fused causal flash attention -----------------------------
// grid (16, BH), 256 thr. Block x handles q-tiles {x, 31-x} (33 kv-tiles
// total -> uniform load). Wave w owns q rows q0+w*16..+15. KV tile = 64.
// K/Vt fragments are read DIRECTLY from global (L1/L2-resident: 256KB/bh) --
// no K/V LDS staging, no __syncthreads anywhere. Only per-wave P LDS buffer.
__global__ __launch_bounds__(256) void attn_kernel(const u16* __restrict__ Q,
                                                   const u16* __restrict__ K,
                                                   const u16* __restrict__ Vt,
                                                   u16* __restrict__ Y) {
    __shared__ char Plds[8192];          // 4 waves x [16][64] bf16, swizzled
    const int t = threadIdx.x;
    const int l = t & 63, w = t >> 6;
    char* Pw = Plds + w * 2048;
    const int g = l >> 4, lr = l & 15;
    const int bh = blockIdx.y;
    const u16* Qb = Q + (size_t)bh * (2048 * 64);
    const u16* Kb = K + (size_t)bh * (2048 * 64);
    const u16* Vb = Vt + (size_t)bh * (64 * 2048);
    const int bb = bh >> 4, hh = bh & 15;

#pragma unroll 1
    for (int job = 0; job < 2; ++job) {
        const int qi = job ? (31 - (int)blockIdx.x) : (int)blockIdx.x;
        const int q0 = qi << 6;
        const int row_lo = q0 + w * 16;

        bf16x8 aq[2];
        {
            const u16* qp = Qb + (size_t)(row_lo + lr) * 64 + g * 8;
            aq[0] = as_bf16x8(*(const u32x4*)qp);
            aq[1] = as_bf16x8(*(const u32x4*)(qp + 32));
        }
        f32x4 o[4];
        float mrow[4], lsum[4];
#pragma unroll
        for (int n = 0; n < 4; ++n)
#pragma unroll
            for (int e = 0; e < 4; ++e) o[n][e] = 0.f;
#pragma unroll
        for (int r = 0; r < 4; ++r) { mrow[r] = -3.0e38f; lsum[r] = 0.f; }

#pragma unroll 1
        for (int it = 0; it <= qi; ++it) {
            const int kv0 = it << 6;
            // ---- QK^T: B-fragments straight from global K ----
            f32x4 s[4];
#pragma unroll
            for (int n = 0; n < 4; ++n) {
                f32x4 z; z[0] = z[1] = z[2] = z[3] = 0.f;
                const u16* kp = Kb + (size_t)(kv0 + n * 16 + lr) * 64 + g * 8;
                z = __builtin_amdgcn_mfma_f32_16x16x32_bf16(
                    aq[0], as_bf16x8(*(const u32x4*)kp), z, 0, 0, 0);
                z = __builtin_amdgcn_mfma_f32_16x16x32_bf16(
                    aq[1], as_bf16x8(*(const u32x4*)(kp + 32)), z, 0, 0, 0);
                s[n] = z;
            }
            // ---- online softmax (per 16-lane row group) ----
            float mt[4], al[4], sm[4];
#pragma unroll
            for (int r = 0; r < 4; ++r) mt[r] = -3.0e38f;
#pragma unroll
            for (int n = 0; n < 4; ++n) {
                const int cg = kv0 + n * 16 + lr;
#pragma unroll
                for (int r = 0; r < 4; ++r) {
                    float v = s[n][r] * 0.125f;
                    v = (cg <= row_lo + g * 4 + r) ? v : -3.0e38f;
                    s[n][r] = v;
                    mt[r] = fmaxf(mt[r], v);
                }
            }
#pragma unroll
            for (int off = 1; off < 16; off <<= 1)
#pragma unroll
                for (int r = 0; r < 4; ++r) mt[r] = fmaxf(mt[r], __shfl_xor(mt[r], off));
#pragma unroll
            for (int r = 0; r < 4; ++r) {
                const float mn = fmaxf(mrow[r], mt[r]);
                al[r] = exp2f((mrow[r] - mn) * 1.44269504f);
                mrow[r] = mn;
                sm[r] = 0.f;
            }
#pragma unroll
            for (int n = 0; n < 4; ++n)
#pragma unroll
                for (int r = 0; r < 4; ++r) {
                    const float p = exp2f((s[n][r] - mrow[r]) * 1.44269504f);
                    s[n][r] = p;
                    sm[r] += p;
                }
#pragma unroll
            for (int off = 1; off < 16; off <<= 1)
#pragma unroll
                for (int r = 0; r < 4; ++r) sm[r] += __shfl_xor(sm[r], off);
#pragma unroll
            for (int r = 0; r < 4; ++r) lsum[r] = lsum[r] * al[r] + sm[r];
#pragma unroll
            for (int n = 0; n < 4; ++n)
#pragma unroll
                for (int r = 0; r < 4; ++r) o[n][r] *= al[r];
            // ---- P -> per-wave LDS (swizzled [16][64], no barrier) ----
#pragma unroll
            for (int n = 0; n < 4; ++n)
#pragma unroll
                for (int r = 0; r < 4; ++r) {
                    const int prow = g * 4 + r;
                    const unsigned off = (unsigned)(prow * 128 + (n * 16 + lr) * 2) ^
                                         (unsigned)((prow & 7) << 4);
                    *(u16*)(Pw + off) = f2bf(s[n][r]);
                }
            bf16x8 ap[2];
#pragma unroll
            for (int kk = 0; kk < 2; ++kk) {
                const unsigned off = (unsigned)(lr * 128 + kk * 64 + g * 16) ^
                                     (unsigned)((lr & 7) << 4);
                ap[kk] = as_bf16x8(*(const u32x4*)(Pw + off));
            }
            // ---- PV: B-fragments straight from global Vt ----
#pragma unroll
            for (int n = 0; n < 4; ++n) {
                const u16* vp = Vb + (size_t)(n * 16 + lr) * 2048 + kv0 + g * 8;
#pragma unroll
                for (int kk = 0; kk < 2; ++kk)
                    o[n] = __builtin_amdgcn_mfma_f32_16x16x32_bf16(
                        ap[kk], as_bf16x8(*(const u32x4*)(vp + kk * 32)), o[n], 0, 0, 0);
            }
        }
        // ---- epilogue: Y[b, t, h*64+d] ----
#pragma unroll
        for (int r = 0; r < 4; ++r) {
            const int tg = row_lo + g * 4 + r;
            const float inv = 1.f / lsum[r];
#pragma unroll
            for (int n = 0; n < 4; ++n)
                Y[((size_t)(bb * 2048 + tg)) * 1024 + hh * 64 + n * 16 + lr] =
                    f2bf(o[n][r] * inv);
        }
    }
}

// ---------------------------------------------------------------------------
extern "C" void kernel_launch(void* const* d_in, const int* in_sizes, int n_in,
                              void* d_out, int out_size, void* d_ws, size_t ws_size,
                              hipStream_t stream) {
    const float* x = (const float*)d_in[0];
    const float* Wqkv = (const float*)d_in[1];
    const float* bqkv = (const float*)d_in[2];
    const float* Wproj = (const float*)d_in[3];
    const float* bproj = (const float*)d_in[4];
    float* out = (float*)d_out;
    char* ws = (char*)d_ws;

    u16* Wtq = (u16*)(ws + 0);            // 3072x1024 bf16  (6.29 MB)
    u16* Wtp = (u16*)(ws + 6291456);      // 1024x1024 bf16  (2.10 MB)
    u16* Qb  = (u16*)(ws + 8388608);      // [B,H,T,64] bf16 (16.78 MB)
    // K at Qb + 8388608 elems, V at Qb + 16777216 elems (contiguous sections)
    u16* Vb  = (u16*)(ws + 41943040);
    u16* Vtb = (u16*)(ws + 58720256);     // [B,H,64,T] bf16
    u16* Yb  = Vb;                        // alias: V dead after transpose

    tcast_f32<<<dim3(16, 48), 256, 0, stream>>>(Wqkv, Wtq, 1024, 3072);
    tcast_f32<<<dim3(16, 16), 256, 0, stream>>>(Wproj, Wtp, 1024, 1024);
    gemm_kernel<0, float><<<dim3(64, 24), 256, 0, stream>>>(
        x, Wtq, bqkv, (void*)Qb, 8192, 3072, 1024);
    tv_bf16<<<dim3(32, 64), 256, 0, stream>>>(Vb, Vtb);
    attn_kernel<<<dim3(16, 64), 256, 0, stream>>>(
        Qb, Qb + 8388608, Vtb, Yb);
    gemm_kernel<1, u16><<<dim3(64, 8), 256, 0, stream>>>(
        Yb, Wtp, bproj, (void*)out, 8192, 1024, 1024);
}

// Round 3
// 378.506 us; speedup vs baseline: 1.0300x; 1.0247x over previous
//
#include <hip/hip_runtime.h>

using u16 = unsigned short;
typedef __attribute__((ext_vector_type(8))) __bf16 bf16x8;
typedef __attribute__((ext_vector_type(4))) float f32x4;
typedef __attribute__((ext_vector_type(16))) float f32x16;
typedef __attribute__((ext_vector_type(4))) unsigned int u32x4;
typedef __attribute__((ext_vector_type(2))) unsigned int u32x2;

__device__ inline u16 f2bf(float f) {
    unsigned u = __float_as_uint(f);
    u += 0x7FFFu + ((u >> 16) & 1u);   // RNE
    return (u16)(u >> 16);
}
__device__ inline unsigned pack2(float a, float b) {
    return (unsigned)f2bf(a) | ((unsigned)f2bf(b) << 16);
}
__device__ inline bf16x8 as_bf16x8(u32x4 v) {
    union { u32x4 u; bf16x8 b; } x; x.u = v; return x.b;
}
__device__ inline unsigned cvtpk(float lo, float hi) {
    unsigned w;
    asm("v_cvt_pk_bf16_f32 %0, %1, %2" : "=v"(w) : "v"(lo), "v"(hi));
    return w;
}

// ---------------- transpose + cast fp32 -> bf16 (for W^T) ----------------
__global__ __launch_bounds__(256) void tcast_f32(const float* __restrict__ in,
                                                 u16* __restrict__ out,
                                                 int R, int C) {
    __shared__ float tile[64][65];
    const int r0 = blockIdx.x * 64, c0 = blockIdx.y * 64;
    const int t = threadIdx.x;
    {
        const int r = t >> 2, cq = (t & 3) * 16;
        const float* src = in + (size_t)(r0 + r) * C + c0 + cq;
#pragma unroll
        for (int j = 0; j < 4; ++j) {
            f32x4 v = *(const f32x4*)(src + j * 4);
#pragma unroll
            for (int e = 0; e < 4; ++e) tile[r][cq + j * 4 + e] = v[e];
        }
    }
    __syncthreads();
    {
        const int c = t >> 2, rq = (t & 3) * 16;
        u32x4 w0, w1;
#pragma unroll
        for (int j = 0; j < 4; ++j) {
            w0[j] = pack2(tile[rq + 2 * j][c], tile[rq + 2 * j + 1][c]);
            w1[j] = pack2(tile[rq + 8 + 2 * j][c], tile[rq + 8 + 2 * j + 1][c]);
        }
        u16* dst = out + (size_t)(c0 + c) * R + r0 + rq;
        *(u32x4*)dst = w0;
        *(u32x4*)(dst + 8) = w1;
    }
}

// ---------------- batched transpose bf16: V [BH][T][64] -> Vt [BH][64][T] ----
__global__ __launch_bounds__(256) void tv_bf16(const u16* __restrict__ V,
                                               u16* __restrict__ Vt) {
    __shared__ u16 tile[64][68];
    const int t0 = blockIdx.x * 64, bh = blockIdx.y;
    const int t = threadIdx.x;
    {
        const int r = t >> 2, cq = (t & 3) * 16;
        const u16* src = V + ((size_t)bh * 2048 + t0 + r) * 64 + cq;
        u32x4 a = *(const u32x4*)src;
        u32x4 b = *(const u32x4*)(src + 8);
#pragma unroll
        for (int j = 0; j < 4; ++j) {
            tile[r][cq + 2 * j] = (u16)(a[j] & 0xFFFFu);
            tile[r][cq + 2 * j + 1] = (u16)(a[j] >> 16);
            tile[r][cq + 8 + 2 * j] = (u16)(b[j] & 0xFFFFu);
            tile[r][cq + 8 + 2 * j + 1] = (u16)(b[j] >> 16);
        }
    }
    __syncthreads();
    {
        const int d = t >> 2, rq = (t & 3) * 16;
        u32x4 w0, w1;
#pragma unroll
        for (int j = 0; j < 4; ++j) {
            w0[j] = (unsigned)tile[rq + 2 * j][d] | ((unsigned)tile[rq + 2 * j + 1][d] << 16);
            w1[j] = (unsigned)tile[rq + 8 + 2 * j][d] | ((unsigned)tile[rq + 8 + 2 * j + 1][d] << 16);
        }
        u16* dst = Vt + ((size_t)bh * 64 + d) * 2048 + t0 + rq;
        *(u32x4*)dst = w0;
        *(u32x4*)(dst + 8) = w1;
    }
}

// ---------------- GEMM (unchanged from R2) ---------------------------------
template <int EPI, typename TA>
__global__ __launch_bounds__(256) void gemm_kernel(const TA* __restrict__ A,
                                                   const u16* __restrict__ Bt,
                                                   const float* __restrict__ bias,
                                                   void* __restrict__ outp,
                                                   const int M, const int N, const int K) {
    __shared__ char lds[16384];
    char* As = lds;
    char* Bs = lds + 8192;
    const int t = threadIdx.x;
    const int l = t & 63, wid = t >> 6;
    const int wr = wid >> 1, wc = wid & 1;
    const int g = l >> 4, lr = l & 15;
    const int m0 = blockIdx.x * 128, n0 = blockIdx.y * 128;

    f32x4 acc[4][4];
#pragma unroll
    for (int i = 0; i < 4; ++i)
#pragma unroll
        for (int j = 0; j < 4; ++j)
#pragma unroll
            for (int e = 0; e < 4; ++e) acc[i][j][e] = 0.f;

    const int srow = t >> 2;
    const int sk = (t & 3) * 8;

    for (int k0 = 0; k0 < K; k0 += 32) {
#pragma unroll
        for (int j = 0; j < 2; ++j) {
            const int row = srow + j * 64;
            u32x4 w;
            const TA* src = A + (size_t)(m0 + row) * K + k0 + sk;
            if constexpr (sizeof(TA) == 2) {
                w = *(const u32x4*)src;
            } else {
                f32x4 p0 = *(const f32x4*)src;
                f32x4 p1 = *(const f32x4*)(src + 4);
                w[0] = pack2(p0[0], p0[1]); w[1] = pack2(p0[2], p0[3]);
                w[2] = pack2(p1[0], p1[1]); w[3] = pack2(p1[2], p1[3]);
            }
            *(u32x4*)(As + row * 64 + sk * 2) = w;
            const u16* srcb = Bt + (size_t)(n0 + row) * K + k0 + sk;
            *(u32x4*)(Bs + row * 64 + sk * 2) = *(const u32x4*)srcb;
        }
        __syncthreads();
        bf16x8 a[4], b[4];
#pragma unroll
        for (int m = 0; m < 4; ++m) {
            const int row = wr * 64 + m * 16 + lr;
            a[m] = as_bf16x8(*(const u32x4*)(As + row * 64 + g * 16));
        }
#pragma unroll
        for (int n = 0; n < 4; ++n) {
            const int row = wc * 64 + n * 16 + lr;
            b[n] = as_bf16x8(*(const u32x4*)(Bs + row * 64 + g * 16));
        }
#pragma unroll
        for (int m = 0; m < 4; ++m)
#pragma unroll
            for (int n = 0; n < 4; ++n)
                acc[m][n] = __builtin_amdgcn_mfma_f32_16x16x32_bf16(a[m], b[n], acc[m][n], 0, 0, 0);
        __syncthreads();
    }

#pragma unroll
    for (int m = 0; m < 4; ++m) {
#pragma unroll
        for (int n = 0; n < 4; ++n) {
            const int colg = n0 + wc * 64 + n * 16 + lr;
            const float bv = bias[colg];
#pragma unroll
            for (int r = 0; r < 4; ++r) {
                const int rowg = m0 + wr * 64 + m * 16 + g * 4 + r;
                const float v = acc[m][n][r] + bv;
                if constexpr (EPI == 0) {
                    const int sec = colg >> 10, c = colg & 1023;
                    const int hh = c >> 6, dd = c & 63;
                    const int bb = rowg >> 11, tt = rowg & 2047;
                    u16* dst = (u16*)outp;
                    dst[(size_t)sec * 8388608u +
                        (((size_t)(bb * 16 + hh) * 2048 + tt) << 6) + dd] = f2bf(v);
                } else {
                    ((float*)outp)[(size_t)rowg * N + colg] = v;
                }
            }
        }
    }
}

// ---------------- fused causal flash attention, swapped-QK^T 32x32 ---------
// grid (16, BH), 256 thr = 4 waves, wave w owns 32 q-rows q0w..q0w+31.
// S^T = mfma_32x32x16(K, Q): lane(q=l&31,hi=l>>5) holds S[kv][q] for
// kv = kvb*32 + (r&3)+8*(r>>2)+4*hi. Softmax fully lane-local (+1 permlane
// swap for the cross-half row reduce). P->A-frag via 16 cvt_pk + 8
// permlane32_swap, all in-register. NO LDS, NO ds_bpermute in main loop.
__global__ __launch_bounds__(256) void attn_kernel(const u16* __restrict__ Q,
                                                   const u16* __restrict__ K,
                                                   const u16* __restrict__ Vt,
                                                   u16* __restrict__ Y) {
    const int t = threadIdx.x;
    const int l = t & 63, w = t >> 6;
    const int q = l & 31, hi = l >> 5;
    const int bh = blockIdx.y;
    const int q0w = blockIdx.x * 128 + w * 32;
    const u16* Qb = Q + (size_t)bh * (2048 * 64);
    const u16* Kb = K + (size_t)bh * (2048 * 64);
    const u16* Vb = Vt + (size_t)bh * (64 * 2048);
    const int bb = bh >> 4, hh = bh & 15;
    const float c = 0.18033688f;           // 0.125 * log2(e)
    const int qg = q0w + q;                // this lane's softmax row

    // Q as B-operand: lane col=q, k = ks*16 + hi*8 + e  (contiguous d)
    bf16x8 qf[4];
#pragma unroll
    for (int ks = 0; ks < 4; ++ks)
        qf[ks] = as_bf16x8(*(const u32x4*)(Qb + (size_t)(q0w + q) * 64 + ks * 16 + hi * 8));

    f32x16 o0, o1;
#pragma unroll
    for (int r = 0; r < 16; ++r) { o0[r] = 0.f; o1[r] = 0.f; }
    float M = -3.0e38f, lsum = 0.f;

    const int nt = ((q0w + 31) >> 6) + 1;
#pragma unroll 1
    for (int it = 0; it < nt; ++it) {
        const int kv0 = it << 6;
        // ---- prefetch V B-frags (consumed after softmax; hides L2 latency)
        // vf[kvb][s][dblk]: Vt[dblk*32+q][kv0 + kvb*32 + s*16 + hi*8 ..+7]
        u32x4 vf[8];
#pragma unroll
        for (int kvb = 0; kvb < 2; ++kvb)
#pragma unroll
            for (int s = 0; s < 2; ++s)
#pragma unroll
                for (int db = 0; db < 2; ++db)
                    vf[kvb * 4 + s * 2 + db] = *(const u32x4*)(
                        Vb + (size_t)(db * 32 + q) * 2048 + kv0 + kvb * 32 + s * 16 + hi * 8);
        // ---- QK^T (swapped): sX[r] = S[kv0 + X*32 + roff(r)][q]
        f32x16 s0, s1;
#pragma unroll
        for (int r = 0; r < 16; ++r) { s0[r] = 0.f; s1[r] = 0.f; }
#pragma unroll
        for (int ks = 0; ks < 4; ++ks) {
            bf16x8 kf0 = as_bf16x8(*(const u32x4*)(
                Kb + (size_t)(kv0 + q) * 64 + ks * 16 + hi * 8));
            s0 = __builtin_amdgcn_mfma_f32_32x32x16_bf16(kf0, qf[ks], s0, 0, 0, 0);
            bf16x8 kf1 = as_bf16x8(*(const u32x4*)(
                Kb + (size_t)(kv0 + 32 + q) * 64 + ks * 16 + hi * 8));
            s1 = __builtin_amdgcn_mfma_f32_32x32x16_bf16(kf1, qf[ks], s1, 0, 0, 0);
        }
        // ---- causal mask (exactly the last tile is diagonal)
        if (it == nt - 1) {
#pragma unroll
            for (int r = 0; r < 16; ++r) {
                const int roff = (r & 3) + 8 * (r >> 2) + hi * 4;
                if (kv0 + roff > qg) s0[r] = -1.0e30f;
                if (kv0 + 32 + roff > qg) s1[r] = -1.0e30f;
            }
        }
        // ---- row max: in-register tree + one permlane32_swap
        float mx[8];
#pragma unroll
        for (int j = 0; j < 8; ++j)
            mx[j] = fmaxf(fmaxf(s0[2 * j], s0[2 * j + 1]), fmaxf(s1[2 * j], s1[2 * j + 1]));
        float pmax = fmaxf(fmaxf(fmaxf(mx[0], mx[1]), fmaxf(mx[2], mx[3])),
                           fmaxf(fmaxf(mx[4], mx[5]), fmaxf(mx[6], mx[7])));
        {
            u32x2 rr = __builtin_amdgcn_permlane32_swap(
                __float_as_uint(pmax), __float_as_uint(pmax), false, false);
            const float part = __uint_as_float(hi ? rr[0] : rr[1]);
            pmax = fmaxf(pmax, part);
        }
        // ---- defer-max (T13): rescale only if max grew past THR
        if (__any(pmax > M + 55.0f)) {
            const float Mn = fmaxf(M, pmax);
            const float al = exp2f((M - Mn) * c);
            M = Mn;
            lsum *= al;
#pragma unroll
            for (int r = 0; r < 16; ++r) {
                const float alq = __shfl(al, (r & 3) + 8 * (r >> 2) + hi * 4);
                o0[r] *= alq;
                o1[r] *= alq;
            }
        }
        // ---- exp + row sum (lane-local, s regs reused as p)
        const float mc = M * c;
        float sm[8];
#pragma unroll
        for (int j = 0; j < 8; ++j) {
            s0[2 * j]     = exp2f(fmaf(s0[2 * j],     c, -mc));
            s0[2 * j + 1] = exp2f(fmaf(s0[2 * j + 1], c, -mc));
            s1[2 * j]     = exp2f(fmaf(s1[2 * j],     c, -mc));
            s1[2 * j + 1] = exp2f(fmaf(s1[2 * j + 1], c, -mc));
            sm[j] = (s0[2 * j] + s0[2 * j + 1]) + (s1[2 * j] + s1[2 * j + 1]);
        }
        float psum = ((sm[0] + sm[1]) + (sm[2] + sm[3])) + ((sm[4] + sm[5]) + (sm[6] + sm[7]));
        {
            u32x2 rr = __builtin_amdgcn_permlane32_swap(
                __float_as_uint(psum), __float_as_uint(psum), false, false);
            psum += __uint_as_float(hi ? rr[0] : rr[1]);
        }
        lsum += psum;
        // ---- P -> A-frags: 8 cvt_pk + 4 swaps per kvb, then PV MFMA
#pragma unroll
        for (int kvb = 0; kvb < 2; ++kvb) {
            unsigned wd[8];
#pragma unroll
            for (int j = 0; j < 8; ++j) {
                const float plo = kvb ? s1[2 * j] : s0[2 * j];
                const float phi = kvb ? s1[2 * j + 1] : s0[2 * j + 1];
                wd[j] = cvtpk(plo, phi);
            }
            u32x2 r0 = __builtin_amdgcn_permlane32_swap(wd[0], wd[2], false, false);
            u32x2 r1 = __builtin_amdgcn_permlane32_swap(wd[1], wd[3], false, false);
            u32x2 r2 = __builtin_amdgcn_permlane32_swap(wd[4], wd[6], false, false);
            u32x2 r3 = __builtin_amdgcn_permlane32_swap(wd[5], wd[7], false, false);
            u32x4 fa, fb;
            fa[0] = r0[0]; fa[1] = r1[0]; fa[2] = r0[1]; fa[3] = r1[1];  // kv s*16: 0-15
            fb[0] = r2[0]; fb[1] = r3[0]; fb[2] = r2[1]; fb[3] = r3[1];  // kv 16-31
            const bf16x8 pa = as_bf16x8(fa), pb = as_bf16x8(fb);
            o0 = __builtin_amdgcn_mfma_f32_32x32x16_bf16(pa, as_bf16x8(vf[kvb * 4 + 0]), o0, 0, 0, 0);
            o1 = __builtin_amdgcn_mfma_f32_32x32x16_bf16(pa, as_bf16x8(vf[kvb * 4 + 1]), o1, 0, 0, 0);
            o0 = __builtin_amdgcn_mfma_f32_32x32x16_bf16(pb, as_bf16x8(vf[kvb * 4 + 2]), o0, 0, 0, 0);
            o1 = __builtin_amdgcn_mfma_f32_32x32x16_bf16(pb, as_bf16x8(vf[kvb * 4 + 3]), o1, 0, 0, 0);
        }
    }
    // ---- epilogue: O lane layout is (col d = l&31, row q = roff(r))
    const float linv = 1.f / lsum;
#pragma unroll
    for (int r = 0; r < 16; ++r) {
        const int roff = (r & 3) + 8 * (r >> 2) + hi * 4;
        const float invq = __shfl(linv, roff);
        const size_t base = ((size_t)(bb * 2048 + q0w + roff)) * 1024 + hh * 64 + q;
        Y[base] = f2bf(o0[r] * invq);
        Y[base + 32] = f2bf(o1[r] * invq);
    }
}

// ---------------------------------------------------------------------------
extern "C" void kernel_launch(void* const* d_in, const int* in_sizes, int n_in,
                              void* d_out, int out_size, void* d_ws, size_t ws_size,
                              hipStream_t stream) {
    const float* x = (const float*)d_in[0];
    const float* Wqkv = (const float*)d_in[1];
    const float* bqkv = (const float*)d_in[2];
    const float* Wproj = (const float*)d_in[3];
    const float* bproj = (const float*)d_in[4];
    float* out = (float*)d_out;
    char* ws = (char*)d_ws;

    u16* Wtq = (u16*)(ws + 0);            // 3072x1024 bf16  (6.29 MB)
    u16* Wtp = (u16*)(ws + 6291456);      // 1024x1024 bf16  (2.10 MB)
    u16* Qb  = (u16*)(ws + 8388608);      // [B,H,T,64] bf16 (16.78 MB)
    u16* Vb  = (u16*)(ws + 41943040);
    u16* Vtb = (u16*)(ws + 58720256);     // [B,H,64,T] bf16
    u16* Yb  = Vb;                        // alias: V dead after transpose

    tcast_f32<<<dim3(16, 48), 256, 0, stream>>>(Wqkv, Wtq, 1024, 3072);
    tcast_f32<<<dim3(16, 16), 256, 0, stream>>>(Wproj, Wtp, 1024, 1024);
    gemm_kernel<0, float><<<dim3(64, 24), 256, 0, stream>>>(
        x, Wtq, bqkv, (void*)Qb, 8192, 3072, 1024);
    tv_bf16<<<dim3(32, 64), 256, 0, stream>>>(Vb, Vtb);
    attn_kernel<<<dim3(16, 64), 256, 0, stream>>>(
        Qb, Qb + 8388608, Vtb, Yb);
    gemm_kernel<1, u16><<<dim3(64, 8), 256, 0, stream>>>(
        Yb, Wtp, bproj, (void*)out, 8192, 1024, 1024);
}

// Round 4
// 263.709 us; speedup vs baseline: 1.4783x; 1.4353x over previous
//
#include <hip/hip_runtime.h>

using u16 = unsigned short;
typedef __attribute__((ext_vector_type(8))) __bf16 bf16x8;
typedef __attribute__((ext_vector_type(4))) float f32x4;
typedef __attribute__((ext_vector_type(16))) float f32x16;
typedef __attribute__((ext_vector_type(4))) unsigned int u32x4;
typedef __attribute__((ext_vector_type(2))) unsigned int u32x2;

__device__ inline u16 f2bf(float f) {
    unsigned u = __float_as_uint(f);
    u += 0x7FFFu + ((u >> 16) & 1u);   // RNE
    return (u16)(u >> 16);
}
__device__ inline unsigned pack2(float a, float b) {
    return (unsigned)f2bf(a) | ((unsigned)f2bf(b) << 16);
}
__device__ inline bf16x8 as_bf16x8(u32x4 v) {
    union { u32x4 u; bf16x8 b; } x; x.u = v; return x.b;
}
__device__ inline unsigned cvtpk(float lo, float hi) {
    unsigned w;
    asm("v_cvt_pk_bf16_f32 %0, %1, %2" : "=v"(w) : "v"(lo), "v"(hi));
    return w;
}
__device__ inline void gload_lds16(const void* g, void* l) {
    __builtin_amdgcn_global_load_lds(
        (const __attribute__((address_space(1))) void*)g,
        (__attribute__((address_space(3))) void*)l, 16, 0, 0);
}

// ---------------- transpose + cast fp32 -> bf16 (for W^T) ----------------
__global__ __launch_bounds__(256) void tcast_f32(const float* __restrict__ in,
                                                 u16* __restrict__ out,
                                                 int R, int C) {
    __shared__ float tile[64][65];
    const int r0 = blockIdx.x * 64, c0 = blockIdx.y * 64;
    const int t = threadIdx.x;
    {
        const int r = t >> 2, cq = (t & 3) * 16;
        const float* src = in + (size_t)(r0 + r) * C + c0 + cq;
#pragma unroll
        for (int j = 0; j < 4; ++j) {
            f32x4 v = *(const f32x4*)(src + j * 4);
#pragma unroll
            for (int e = 0; e < 4; ++e) tile[r][cq + j * 4 + e] = v[e];
        }
    }
    __syncthreads();
    {
        const int c = t >> 2, rq = (t & 3) * 16;
        u32x4 w0, w1;
#pragma unroll
        for (int j = 0; j < 4; ++j) {
            w0[j] = pack2(tile[rq + 2 * j][c], tile[rq + 2 * j + 1][c]);
            w1[j] = pack2(tile[rq + 8 + 2 * j][c], tile[rq + 8 + 2 * j + 1][c]);
        }
        u16* dst = out + (size_t)(c0 + c) * R + r0 + rq;
        *(u32x4*)dst = w0;
        *(u32x4*)(dst + 8) = w1;
    }
}

// ---------------- batched transpose bf16: V [BH][T][64] -> Vt [BH][64][T] ----
__global__ __launch_bounds__(256) void tv_bf16(const u16* __restrict__ V,
                                               u16* __restrict__ Vt) {
    __shared__ u16 tile[64][68];
    const int t0 = blockIdx.x * 64, bh = blockIdx.y;
    const int t = threadIdx.x;
    {
        const int r = t >> 2, cq = (t & 3) * 16;
        const u16* src = V + ((size_t)bh * 2048 + t0 + r) * 64 + cq;
        u32x4 a = *(const u32x4*)src;
        u32x4 b = *(const u32x4*)(src + 8);
#pragma unroll
        for (int j = 0; j < 4; ++j) {
            tile[r][cq + 2 * j] = (u16)(a[j] & 0xFFFFu);
            tile[r][cq + 2 * j + 1] = (u16)(a[j] >> 16);
            tile[r][cq + 8 + 2 * j] = (u16)(b[j] & 0xFFFFu);
            tile[r][cq + 8 + 2 * j + 1] = (u16)(b[j] >> 16);
        }
    }
    __syncthreads();
    {
        const int d = t >> 2, rq = (t & 3) * 16;
        u32x4 w0, w1;
#pragma unroll
        for (int j = 0; j < 4; ++j) {
            w0[j] = (unsigned)tile[rq + 2 * j][d] | ((unsigned)tile[rq + 2 * j + 1][d] << 16);
            w1[j] = (unsigned)tile[rq + 8 + 2 * j][d] | ((unsigned)tile[rq + 8 + 2 * j + 1][d] << 16);
        }
        u16* dst = Vt + ((size_t)bh * 64 + d) * 2048 + t0 + rq;
        *(u32x4*)dst = w0;
        *(u32x4*)(dst + 8) = w1;
    }
}

// ---------------- GEMM (unchanged) -----------------------------------------
template <int EPI, typename TA>
__global__ __launch_bounds__(256) void gemm_kernel(const TA* __restrict__ A,
                                                   const u16* __restrict__ Bt,
                                                   const float* __restrict__ bias,
                                                   void* __restrict__ outp,
                                                   const int M, const int N, const int K) {
    __shared__ char lds[16384];
    char* As = lds;
    char* Bs = lds + 8192;
    const int t = threadIdx.x;
    const int l = t & 63, wid = t >> 6;
    const int wr = wid >> 1, wc = wid & 1;
    const int g = l >> 4, lr = l & 15;
    const int m0 = blockIdx.x * 128, n0 = blockIdx.y * 128;

    f32x4 acc[4][4];
#pragma unroll
    for (int i = 0; i < 4; ++i)
#pragma unroll
        for (int j = 0; j < 4; ++j)
#pragma unroll
            for (int e = 0; e < 4; ++e) acc[i][j][e] = 0.f;

    const int srow = t >> 2;
    const int sk = (t & 3) * 8;

    for (int k0 = 0; k0 < K; k0 += 32) {
#pragma unroll
        for (int j = 0; j < 2; ++j) {
            const int row = srow + j * 64;
            u32x4 w;
            const TA* src = A + (size_t)(m0 + row) * K + k0 + sk;
            if constexpr (sizeof(TA) == 2) {
                w = *(const u32x4*)src;
            } else {
                f32x4 p0 = *(const f32x4*)src;
                f32x4 p1 = *(const f32x4*)(src + 4);
                w[0] = pack2(p0[0], p0[1]); w[1] = pack2(p0[2], p0[3]);
                w[2] = pack2(p1[0], p1[1]); w[3] = pack2(p1[2], p1[3]);
            }
            *(u32x4*)(As + row * 64 + sk * 2) = w;
            const u16* srcb = Bt + (size_t)(n0 + row) * K + k0 + sk;
            *(u32x4*)(Bs + row * 64 + sk * 2) = *(const u32x4*)srcb;
        }
        __syncthreads();
        bf16x8 a[4], b[4];
#pragma unroll
        for (int m = 0; m < 4; ++m) {
            const int row = wr * 64 + m * 16 + lr;
            a[m] = as_bf16x8(*(const u32x4*)(As + row * 64 + g * 16));
        }
#pragma unroll
        for (int n = 0; n < 4; ++n) {
            const int row = wc * 64 + n * 16 + lr;
            b[n] = as_bf16x8(*(const u32x4*)(Bs + row * 64 + g * 16));
        }
#pragma unroll
        for (int m = 0; m < 4; ++m)
#pragma unroll
            for (int n = 0; n < 4; ++n)
                acc[m][n] = __builtin_amdgcn_mfma_f32_16x16x32_bf16(a[m], b[n], acc[m][n], 0, 0, 0);
        __syncthreads();
    }

#pragma unroll
    for (int m = 0; m < 4; ++m) {
#pragma unroll
        for (int n = 0; n < 4; ++n) {
            const int colg = n0 + wc * 64 + n * 16 + lr;
            const float bv = bias[colg];
#pragma unroll
            for (int r = 0; r < 4; ++r) {
                const int rowg = m0 + wr * 64 + m * 16 + g * 4 + r;
                const float v = acc[m][n][r] + bv;
                if constexpr (EPI == 0) {
                    const int sec = colg >> 10, c = colg & 1023;
                    const int hh = c >> 6, dd = c & 63;
                    const int bb = rowg >> 11, tt = rowg & 2047;
                    u16* dst = (u16*)outp;
                    dst[(size_t)sec * 8388608u +
                        (((size_t)(bb * 16 + hh) * 2048 + tt) << 6) + dd] = f2bf(v);
                } else {
                    ((float*)outp)[(size_t)rowg * N + colg] = v;
                }
            }
        }
    }
}

// ---------------- fused causal flash attention, R4 -------------------------
// grid (8, BH), 256 thr = 4 waves; block handles q-positions {p, 15-p}
// (128 rows each; wave w owns rows p*128+w*32..+31) -> uniform 34 tile-iters.
// K/V tiles double-buffered in LDS via global_load_lds (16B, pre-swizzled
// source, swizzled ds_read). Softmax fully in-register (swapped QK^T 32x32).
__global__ __launch_bounds__(256) void attn_kernel(const u16* __restrict__ Q,
                                                   const u16* __restrict__ K,
                                                   const u16* __restrict__ Vt,
                                                   u16* __restrict__ Y) {
    __shared__ char lds[32768];        // [2 buf][ K 8KB | V 8KB ]
    const int t = threadIdx.x;
    const int l = t & 63, w = t >> 6;
    const int q = l & 31, hi = l >> 5;
    const int bh = blockIdx.y;
    const char* Kby = (const char*)(K + (size_t)bh * (2048 * 64));
    const char* Vby = (const char*)(Vt + (size_t)bh * (64 * 2048));
    const u16* Qb = Q + (size_t)bh * (2048 * 64);
    const int bb = bh >> 4, hh = bh & 15;
    const float c = 0.18033688f;       // 0.125 * log2(e)
    // staging lane geometry
    const int sr8 = l >> 3;            // 0..7 row-within-8
    const int scb = (l & 7) * 16;      // byte col 0..112
    const unsigned rd_swz = (unsigned)((q & 7) << 4);

#pragma unroll 1
    for (int job = 0; job < 2; ++job) {
        const int p = job ? (15 - (int)blockIdx.x) : (int)blockIdx.x;
        const int q0w = p * 128 + w * 32;
        const int qg = q0w + q;
        const int NT = 2 * p + 2;                    // block-uniform tile count
        const int ntw = ((q0w + 31) >> 6) + 1;       // this wave's tile count

        bf16x8 qf[4];
#pragma unroll
        for (int ks = 0; ks < 4; ++ks)
            qf[ks] = as_bf16x8(*(const u32x4*)(Qb + (size_t)(q0w + q) * 64 + ks * 16 + hi * 8));

        f32x16 o0, o1;
#pragma unroll
        for (int r = 0; r < 16; ++r) { o0[r] = 0.f; o1[r] = 0.f; }
        float M = -3.0e38f, lsum = 0.f;

        // ---- stage lambda: tile it -> buffer b (4 gload_lds per wave) ----
        auto STAGE = [&](int it, int b) {
            const int kv0 = it << 6;
            char* Kd = lds + b * 16384 + w * 2048;
            char* Vd = lds + b * 16384 + 8192 + w * 2048;
#pragma unroll
            for (int cc = 0; cc < 2; ++cc) {
                const int r = w * 16 + cc * 8 + sr8;
                const int ck = scb ^ ((r & 7) << 4);
                gload_lds16(Kby + (size_t)(kv0 + r) * 128 + ck, Kd + cc * 1024);
                gload_lds16(Vby + (size_t)r * 4096 + (size_t)kv0 * 2 + ck, Vd + cc * 1024);
            }
        };

        STAGE(0, 0);
        __syncthreads();
        int cur = 0;
#pragma unroll 1
        for (int it = 0; it < NT; ++it) {
            if (it + 1 < NT) STAGE(it + 1, cur ^ 1);
            if (it < ntw) {
                const int kv0 = it << 6;
                const char* Kl = lds + cur * 16384;
                const char* Vl = Kl + 8192;
                // ---- V frags from LDS (swizzled) ----
                u32x4 vf[8];
#pragma unroll
                for (int kvb = 0; kvb < 2; ++kvb)
#pragma unroll
                    for (int s = 0; s < 2; ++s)
#pragma unroll
                        for (int db = 0; db < 2; ++db)
                            vf[kvb * 4 + s * 2 + db] = *(const u32x4*)(
                                Vl + (unsigned)((db * 32 + q) * 128) +
                                ((unsigned)(kvb * 64 + s * 32 + hi * 16) ^ rd_swz));
                // ---- QK^T (swapped) from LDS K ----
                f32x16 s0, s1;
#pragma unroll
                for (int r = 0; r < 16; ++r) { s0[r] = 0.f; s1[r] = 0.f; }
#pragma unroll
                for (int ks = 0; ks < 4; ++ks) {
                    const unsigned co = (unsigned)(ks * 32 + hi * 16) ^ rd_swz;
                    bf16x8 kf0 = as_bf16x8(*(const u32x4*)(Kl + (unsigned)(q * 128) + co));
                    s0 = __builtin_amdgcn_mfma_f32_32x32x16_bf16(kf0, qf[ks], s0, 0, 0, 0);
                    bf16x8 kf1 = as_bf16x8(*(const u32x4*)(Kl + (unsigned)((32 + q) * 128) + co));
                    s1 = __builtin_amdgcn_mfma_f32_32x32x16_bf16(kf1, qf[ks], s1, 0, 0, 0);
                }
                // ---- causal mask (only near-diagonal tiles) ----
                if (kv0 + 63 > q0w) {
#pragma unroll
                    for (int r = 0; r < 16; ++r) {
                        const int roff = (r & 3) + 8 * (r >> 2) + hi * 4;
                        if (kv0 + roff > qg) s0[r] = -1.0e30f;
                        if (kv0 + 32 + roff > qg) s1[r] = -1.0e30f;
                    }
                }
                // ---- row max (in-register + 1 permlane swap) ----
                float mx[8];
#pragma unroll
                for (int j = 0; j < 8; ++j)
                    mx[j] = fmaxf(fmaxf(s0[2 * j], s0[2 * j + 1]),
                                  fmaxf(s1[2 * j], s1[2 * j + 1]));
                float pmax = fmaxf(fmaxf(fmaxf(mx[0], mx[1]), fmaxf(mx[2], mx[3])),
                                   fmaxf(fmaxf(mx[4], mx[5]), fmaxf(mx[6], mx[7])));
                {
                    u32x2 rr = __builtin_amdgcn_permlane32_swap(
                        __float_as_uint(pmax), __float_as_uint(pmax), false, false);
                    pmax = fmaxf(pmax, __uint_as_float(hi ? rr[0] : rr[1]));
                }
                // ---- defer-max rescale ----
                if (__any(pmax > M + 55.0f)) {
                    const float Mn = fmaxf(M, pmax);
                    const float al = exp2f((M - Mn) * c);
                    M = Mn;
                    lsum *= al;
#pragma unroll
                    for (int r = 0; r < 16; ++r) {
                        const float alq = __shfl(al, (r & 3) + 8 * (r >> 2) + hi * 4);
                        o0[r] *= alq;
                        o1[r] *= alq;
                    }
                }
                // ---- exp + row sum ----
                const float mc = M * c;
                float sm[8];
#pragma unroll
                for (int j = 0; j < 8; ++j) {
                    s0[2 * j]     = exp2f(fmaf(s0[2 * j],     c, -mc));
                    s0[2 * j + 1] = exp2f(fmaf(s0[2 * j + 1], c, -mc));
                    s1[2 * j]     = exp2f(fmaf(s1[2 * j],     c, -mc));
                    s1[2 * j + 1] = exp2f(fmaf(s1[2 * j + 1], c, -mc));
                    sm[j] = (s0[2 * j] + s0[2 * j + 1]) + (s1[2 * j] + s1[2 * j + 1]);
                }
                float psum = ((sm[0] + sm[1]) + (sm[2] + sm[3])) +
                             ((sm[4] + sm[5]) + (sm[6] + sm[7]));
                {
                    u32x2 rr = __builtin_amdgcn_permlane32_swap(
                        __float_as_uint(psum), __float_as_uint(psum), false, false);
                    psum += __uint_as_float(hi ? rr[0] : rr[1]);
                }
                lsum += psum;
                // ---- P -> A-frags (cvt_pk + permlane32_swap) + PV ----
#pragma unroll
                for (int kvb = 0; kvb < 2; ++kvb) {
                    unsigned wd[8];
#pragma unroll
                    for (int j = 0; j < 8; ++j) {
                        const float plo = kvb ? s1[2 * j] : s0[2 * j];
                        const float phi = kvb ? s1[2 * j + 1] : s0[2 * j + 1];
                        wd[j] = cvtpk(plo, phi);
                    }
                    u32x2 r0 = __builtin_amdgcn_permlane32_swap(wd[0], wd[2], false, false);
                    u32x2 r1 = __builtin_amdgcn_permlane32_swap(wd[1], wd[3], false, false);
                    u32x2 r2 = __builtin_amdgcn_permlane32_swap(wd[4], wd[6], false, false);
                    u32x2 r3 = __builtin_amdgcn_permlane32_swap(wd[5], wd[7], false, false);
                    u32x4 fa, fb;
                    fa[0] = r0[0]; fa[1] = r1[0]; fa[2] = r0[1]; fa[3] = r1[1];
                    fb[0] = r2[0]; fb[1] = r3[0]; fb[2] = r2[1]; fb[3] = r3[1];
                    const bf16x8 pa = as_bf16x8(fa), pb = as_bf16x8(fb);
                    o0 = __builtin_amdgcn_mfma_f32_32x32x16_bf16(pa, as_bf16x8(vf[kvb * 4 + 0]), o0, 0, 0, 0);
                    o1 = __builtin_amdgcn_mfma_f32_32x32x16_bf16(pa, as_bf16x8(vf[kvb * 4 + 1]), o1, 0, 0, 0);
                    o0 = __builtin_amdgcn_mfma_f32_32x32x16_bf16(pb, as_bf16x8(vf[kvb * 4 + 2]), o0, 0, 0, 0);
                    o1 = __builtin_amdgcn_mfma_f32_32x32x16_bf16(pb, as_bf16x8(vf[kvb * 4 + 3]), o1, 0, 0, 0);
                }
            }
            __syncthreads();
            cur ^= 1;
        }
        // ---- epilogue ----
        const float linv = 1.f / lsum;
#pragma unroll
        for (int r = 0; r < 16; ++r) {
            const int roff = (r & 3) + 8 * (r >> 2) + hi * 4;
            const float invq = __shfl(linv, roff);
            const size_t base = ((size_t)(bb * 2048 + q0w + roff)) * 1024 + hh * 64 + q;
            Y[base] = f2bf(o0[r] * invq);
            Y[base + 32] = f2bf(o1[r] * invq);
        }
    }
}

// ---------------------------------------------------------------------------
extern "C" void kernel_launch(void* const* d_in, const int* in_sizes, int n_in,
                              void* d_out, int out_size, void* d_ws, size_t ws_size,
                              hipStream_t stream) {
    const float* x = (const float*)d_in[0];
    const float* Wqkv = (const float*)d_in[1];
    const float* bqkv = (const float*)d_in[2];
    const float* Wproj = (const float*)d_in[3];
    const float* bproj = (const float*)d_in[4];
    float* out = (float*)d_out;
    char* ws = (char*)d_ws;

    u16* Wtq = (u16*)(ws + 0);            // 3072x1024 bf16
    u16* Wtp = (u16*)(ws + 6291456);      // 1024x1024 bf16
    u16* Qb  = (u16*)(ws + 8388608);      // [B,H,T,64] bf16 x3 (Q,K,V)
    u16* Vb  = (u16*)(ws + 41943040);
    u16* Vtb = (u16*)(ws + 58720256);     // [B,H,64,T] bf16
    u16* Yb  = Vb;                        // alias: V dead after transpose

    tcast_f32<<<dim3(16, 48), 256, 0, stream>>>(Wqkv, Wtq, 1024, 3072);
    tcast_f32<<<dim3(16, 16), 256, 0, stream>>>(Wproj, Wtp, 1024, 1024);
    gemm_kernel<0, float><<<dim3(64, 24), 256, 0, stream>>>(
        x, Wtq, bqkv, (void*)Qb, 8192, 3072, 1024);
    tv_bf16<<<dim3(32, 64), 256, 0, stream>>>(Vb, Vtb);
    attn_kernel<<<dim3(8, 64), 256, 0, stream>>>(
        Qb, Qb + 8388608, Vtb, Yb);
    gemm_kernel<1, u16><<<dim3(64, 8), 256, 0, stream>>>(
        Yb, Wtp, bproj, (void*)out, 8192, 1024, 1024);
}

// Round 5
// 195.185 us; speedup vs baseline: 1.9973x; 1.3511x over previous
//
#include <hip/hip_runtime.h>

using u16 = unsigned short;
typedef __attribute__((ext_vector_type(8))) __bf16 bf16x8;
typedef __attribute__((ext_vector_type(4))) float f32x4;
typedef __attribute__((ext_vector_type(16))) float f32x16;
typedef __attribute__((ext_vector_type(4))) unsigned int u32x4;
typedef __attribute__((ext_vector_type(2))) unsigned int u32x2;

__device__ inline u16 f2bf(float f) {
    unsigned u = __float_as_uint(f);
    u += 0x7FFFu + ((u >> 16) & 1u);   // RNE
    return (u16)(u >> 16);
}
__device__ inline unsigned pack2(float a, float b) {
    return (unsigned)f2bf(a) | ((unsigned)f2bf(b) << 16);
}
__device__ inline bf16x8 as_bf16x8(u32x4 v) {
    union { u32x4 u; bf16x8 b; } x; x.u = v; return x.b;
}
__device__ inline unsigned cvtpk(float lo, float hi) {
    unsigned w;
    asm("v_cvt_pk_bf16_f32 %0, %1, %2" : "=v"(w) : "v"(lo), "v"(hi));
    return w;
}
__device__ inline void gload_lds16(const void* g, void* l) {
    __builtin_amdgcn_global_load_lds(
        (const __attribute__((address_space(1))) void*)g,
        (__attribute__((address_space(3))) void*)l, 16, 0, 0);
}

// ---------------- elementwise cast fp32 -> bf16 (x) ------------------------
__global__ __launch_bounds__(256) void xcast(const float* __restrict__ in,
                                             u16* __restrict__ out) {
    const size_t i = ((size_t)blockIdx.x * 256 + threadIdx.x) * 8;
    f32x4 a = *(const f32x4*)(in + i);
    f32x4 b = *(const f32x4*)(in + i + 4);
    u32x4 w;
    w[0] = pack2(a[0], a[1]); w[1] = pack2(a[2], a[3]);
    w[2] = pack2(b[0], b[1]); w[3] = pack2(b[2], b[3]);
    *(u32x4*)(out + i) = w;
}

// ---------------- transpose + cast fp32 -> bf16 (for W^T) ----------------
__global__ __launch_bounds__(256) void tcast_f32(const float* __restrict__ in,
                                                 u16* __restrict__ out,
                                                 int R, int C) {
    __shared__ float tile[64][65];
    const int r0 = blockIdx.x * 64, c0 = blockIdx.y * 64;
    const int t = threadIdx.x;
    {
        const int r = t >> 2, cq = (t & 3) * 16;
        const float* src = in + (size_t)(r0 + r) * C + c0 + cq;
#pragma unroll
        for (int j = 0; j < 4; ++j) {
            f32x4 v = *(const f32x4*)(src + j * 4);
#pragma unroll
            for (int e = 0; e < 4; ++e) tile[r][cq + j * 4 + e] = v[e];
        }
    }
    __syncthreads();
    {
        const int c = t >> 2, rq = (t & 3) * 16;
        u32x4 w0, w1;
#pragma unroll
        for (int j = 0; j < 4; ++j) {
            w0[j] = pack2(tile[rq + 2 * j][c], tile[rq + 2 * j + 1][c]);
            w1[j] = pack2(tile[rq + 8 + 2 * j][c], tile[rq + 8 + 2 * j + 1][c]);
        }
        u16* dst = out + (size_t)(c0 + c) * R + r0 + rq;
        *(u32x4*)dst = w0;
        *(u32x4*)(dst + 8) = w1;
    }
}

// ---------------- batched transpose bf16: V [BH][T][64] -> Vt [BH][64][T] ----
__global__ __launch_bounds__(256) void tv_bf16(const u16* __restrict__ V,
                                               u16* __restrict__ Vt) {
    __shared__ u16 tile[64][68];
    const int t0 = blockIdx.x * 64, bh = blockIdx.y;
    const int t = threadIdx.x;
    {
        const int r = t >> 2, cq = (t & 3) * 16;
        const u16* src = V + ((size_t)bh * 2048 + t0 + r) * 64 + cq;
        u32x4 a = *(const u32x4*)src;
        u32x4 b = *(const u32x4*)(src + 8);
#pragma unroll
        for (int j = 0; j < 4; ++j) {
            tile[r][cq + 2 * j] = (u16)(a[j] & 0xFFFFu);
            tile[r][cq + 2 * j + 1] = (u16)(a[j] >> 16);
            tile[r][cq + 8 + 2 * j] = (u16)(b[j] & 0xFFFFu);
            tile[r][cq + 8 + 2 * j + 1] = (u16)(b[j] >> 16);
        }
    }
    __syncthreads();
    {
        const int d = t >> 2, rq = (t & 3) * 16;
        u32x4 w0, w1;
#pragma unroll
        for (int j = 0; j < 4; ++j) {
            w0[j] = (unsigned)tile[rq + 2 * j][d] | ((unsigned)tile[rq + 2 * j + 1][d] << 16);
            w1[j] = (unsigned)tile[rq + 8 + 2 * j][d] | ((unsigned)tile[rq + 8 + 2 * j + 1][d] << 16);
        }
        u16* dst = Vt + ((size_t)bh * 64 + d) * 2048 + t0 + rq;
        *(u32x4*)dst = w0;
        *(u32x4*)(dst + 8) = w1;
    }
}

// ---------------- GEMM: A [M][K] bf16 x Bt [N][K] bf16 + bias --------------
// 128x128 tile, BK=32, 256 thr, m97 structure: global_load_lds width-16
// staging for A and B, single LDS buffer, 2 barriers/K-step.
template <int EPI>
__global__ __launch_bounds__(256) void gemm_kernel(const u16* __restrict__ A,
                                                   const u16* __restrict__ Bt,
                                                   const float* __restrict__ bias,
                                                   void* __restrict__ outp,
                                                   const int M, const int N, const int K) {
    __shared__ char lds[16384];
    char* As = lds;
    char* Bs = lds + 8192;
    const int t = threadIdx.x;
    const int l = t & 63, wid = t >> 6;
    const int wr = wid >> 1, wc = wid & 1;
    const int g = l >> 4, lr = l & 15;
    const int m0 = blockIdx.x * 128, n0 = blockIdx.y * 128;

    f32x4 acc[4][4];
#pragma unroll
    for (int i = 0; i < 4; ++i)
#pragma unroll
        for (int j = 0; j < 4; ++j)
#pragma unroll
            for (int e = 0; e < 4; ++e) acc[i][j][e] = 0.f;

    const int srow = l >> 2;          // 0..15 within-wave row
    const int sby = (l & 3) * 16;     // byte col within 64B row
    const size_t Kb2 = (size_t)K * 2;

    for (int k0 = 0; k0 < K; k0 += 32) {
        const size_t kb = (size_t)k0 * 2 + sby;
#pragma unroll
        for (int j = 0; j < 2; ++j) {
            const int row = j * 64 + wid * 16 + srow;
            gload_lds16((const char*)A + (size_t)(m0 + row) * Kb2 + kb,
                        As + j * 4096 + wid * 1024);
            gload_lds16((const char*)Bt + (size_t)(n0 + row) * Kb2 + kb,
                        Bs + j * 4096 + wid * 1024);
        }
        __syncthreads();
        bf16x8 a[4], b[4];
#pragma unroll
        for (int m = 0; m < 4; ++m) {
            const int row = wr * 64 + m * 16 + lr;
            a[m] = as_bf16x8(*(const u32x4*)(As + row * 64 + g * 16));
        }
#pragma unroll
        for (int n = 0; n < 4; ++n) {
            const int row = wc * 64 + n * 16 + lr;
            b[n] = as_bf16x8(*(const u32x4*)(Bs + row * 64 + g * 16));
        }
        __builtin_amdgcn_s_setprio(1);
#pragma unroll
        for (int m = 0; m < 4; ++m)
#pragma unroll
            for (int n = 0; n < 4; ++n)
                acc[m][n] = __builtin_amdgcn_mfma_f32_16x16x32_bf16(a[m], b[n], acc[m][n], 0, 0, 0);
        __builtin_amdgcn_s_setprio(0);
        __syncthreads();
    }

#pragma unroll
    for (int m = 0; m < 4; ++m) {
#pragma unroll
        for (int n = 0; n < 4; ++n) {
            const int colg = n0 + wc * 64 + n * 16 + lr;
            const float bv = bias[colg];
#pragma unroll
            for (int r = 0; r < 4; ++r) {
                const int rowg = m0 + wr * 64 + m * 16 + g * 4 + r;
                const float v = acc[m][n][r] + bv;
                if constexpr (EPI == 0) {
                    const int sec = colg >> 10, c = colg & 1023;
                    const int hh = c >> 6, dd = c & 63;
                    const int bb = rowg >> 11, tt = rowg & 2047;
                    u16* dst = (u16*)outp;
                    dst[(size_t)sec * 8388608u +
                        (((size_t)(bb * 16 + hh) * 2048 + tt) << 6) + dd] = f2bf(v);
                } else {
                    ((float*)outp)[(size_t)rowg * N + colg] = v;
                }
            }
        }
    }
}

// ---------------- fused causal flash attention, R5 -------------------------
// grid (4, BH), 512 thr = 8 waves; block handles q-positions {p, 7-p}
// (256 rows each; wave w owns rows p*256+w*32..+31) -> uniform 36 iters.
// 4-deep LDS ring (64KB) staged via global_load_lds; counted vmcnt (never 0
// mid-loop) + ONE raw s_barrier per iter. Softmax in-register (swapped QK^T).
__global__ __launch_bounds__(512) void attn_kernel(const u16* __restrict__ Q,
                                                   const u16* __restrict__ K,
                                                   const u16* __restrict__ Vt,
                                                   u16* __restrict__ Y) {
    __shared__ char lds[65536];        // 4 bufs x (K 8KB | V 8KB)
    const int t = threadIdx.x;
    const int l = t & 63, w = t >> 6;  // 8 waves
    const int q = l & 31, hi = l >> 5;
    const int bh = blockIdx.y;
    const char* Kby = (const char*)(K + (size_t)bh * 131072);
    const char* Vby = (const char*)(Vt + (size_t)bh * 131072);
    const u16* Qb = Q + (size_t)bh * 131072;
    const int bb = bh >> 4, hh = bh & 15;
    const float c = 0.18033688f;       // 0.125 * log2(e)
    // staging geometry: lane stages row sr = w*8 + (l>>3), slot l&7, swizzled src
    const int sr = w * 8 + (l >> 3);
    const unsigned ck = (unsigned)(((l & 7) ^ (l >> 3)) << 4);
    const unsigned rd_swz = (unsigned)((q & 7) << 4);

#pragma unroll 1
    for (int job = 0; job < 2; ++job) {
        const int p = job ? (7 - (int)blockIdx.x) : (int)blockIdx.x;
        const int q0w = p * 256 + w * 32;
        const int qg = q0w + q;
        const int NT = 4 * p + 4;                 // block-uniform tile count
        const int ntw = ((q0w + 31) >> 6) + 1;    // this wave's tile count

        bf16x8 qf[4];
#pragma unroll
        for (int ks = 0; ks < 4; ++ks)
            qf[ks] = as_bf16x8(*(const u32x4*)(Qb + (size_t)(q0w + q) * 64 + ks * 16 + hi * 8));

        f32x16 o0, o1;
#pragma unroll
        for (int r = 0; r < 16; ++r) { o0[r] = 0.f; o1[r] = 0.f; }
        float M = -3.0e38f, lsum = 0.f;

        // stage tile it -> ring buffer b (2 gload_lds per lane: 1 K + 1 V)
        auto STAGE = [&](int it, int b) {
            const int kv0 = it << 6;
            char* base = lds + b * 16384;
            gload_lds16(Kby + (size_t)(kv0 + sr) * 128 + ck, base + w * 1024);
            gload_lds16(Vby + (size_t)sr * 4096 + (size_t)kv0 * 2 + ck,
                        base + 8192 + w * 1024);
        };

        STAGE(0, 0); STAGE(1, 1); STAGE(2, 2);
#pragma unroll 1
        for (int it = 0; it < NT; ++it) {
            if (it + 2 < NT)      asm volatile("s_waitcnt vmcnt(4)" ::: "memory");
            else if (it + 1 < NT) asm volatile("s_waitcnt vmcnt(2)" ::: "memory");
            else                  asm volatile("s_waitcnt vmcnt(0)" ::: "memory");
            __builtin_amdgcn_s_barrier();
            if (it + 3 < NT) STAGE(it + 3, (it + 3) & 3);
            if (it < ntw) {
                const int kv0 = it << 6;
                const char* Kl = lds + (it & 3) * 16384;
                const char* Vl = Kl + 8192;
                // ---- V frags from LDS (swizzled), issued early ----
                u32x4 vf[8];
#pragma unroll
                for (int kvb = 0; kvb < 2; ++kvb)
#pragma unroll
                    for (int s = 0; s < 2; ++s)
#pragma unroll
                        for (int db = 0; db < 2; ++db)
                            vf[kvb * 4 + s * 2 + db] = *(const u32x4*)(
                                Vl + (unsigned)((db * 32 + q) * 128) +
                                ((unsigned)(kvb * 64 + s * 32 + hi * 16) ^ rd_swz));
                // ---- QK^T (swapped) from LDS K ----
                f32x16 s0, s1;
#pragma unroll
                for (int r = 0; r < 16; ++r) { s0[r] = 0.f; s1[r] = 0.f; }
                __builtin_amdgcn_s_setprio(1);
#pragma unroll
                for (int ks = 0; ks < 4; ++ks) {
                    const unsigned co = (unsigned)(ks * 32 + hi * 16) ^ rd_swz;
                    bf16x8 kf0 = as_bf16x8(*(const u32x4*)(Kl + (unsigned)(q * 128) + co));
                    s0 = __builtin_amdgcn_mfma_f32_32x32x16_bf16(kf0, qf[ks], s0, 0, 0, 0);
                    bf16x8 kf1 = as_bf16x8(*(const u32x4*)(Kl + (unsigned)((32 + q) * 128) + co));
                    s1 = __builtin_amdgcn_mfma_f32_32x32x16_bf16(kf1, qf[ks], s1, 0, 0, 0);
                }
                __builtin_amdgcn_s_setprio(0);
                // ---- causal mask (near-diagonal tiles only) ----
                if (kv0 + 63 > q0w) {
#pragma unroll
                    for (int r = 0; r < 16; ++r) {
                        const int roff = (r & 3) + 8 * (r >> 2) + hi * 4;
                        if (kv0 + roff > qg) s0[r] = -1.0e30f;
                        if (kv0 + 32 + roff > qg) s1[r] = -1.0e30f;
                    }
                }
                // ---- row max (in-register + 1 permlane swap) ----
                float mx[8];
#pragma unroll
                for (int j = 0; j < 8; ++j)
                    mx[j] = fmaxf(fmaxf(s0[2 * j], s0[2 * j + 1]),
                                  fmaxf(s1[2 * j], s1[2 * j + 1]));
                float pmax = fmaxf(fmaxf(fmaxf(mx[0], mx[1]), fmaxf(mx[2], mx[3])),
                                   fmaxf(fmaxf(mx[4], mx[5]), fmaxf(mx[6], mx[7])));
                {
                    u32x2 rr = __builtin_amdgcn_permlane32_swap(
                        __float_as_uint(pmax), __float_as_uint(pmax), false, false);
                    pmax = fmaxf(pmax, __uint_as_float(hi ? rr[0] : rr[1]));
                }
                // ---- defer-max rescale ----
                if (__any(pmax > M + 55.0f)) {
                    const float Mn = fmaxf(M, pmax);
                    const float al = exp2f((M - Mn) * c);
                    M = Mn;
                    lsum *= al;
#pragma unroll
                    for (int r = 0; r < 16; ++r) {
                        const float alq = __shfl(al, (r & 3) + 8 * (r >> 2) + hi * 4);
                        o0[r] *= alq;
                        o1[r] *= alq;
                    }
                }
                // ---- exp + row sum ----
                const float mc = M * c;
                float sm[8];
#pragma unroll
                for (int j = 0; j < 8; ++j) {
                    s0[2 * j]     = exp2f(fmaf(s0[2 * j],     c, -mc));
                    s0[2 * j + 1] = exp2f(fmaf(s0[2 * j + 1], c, -mc));
                    s1[2 * j]     = exp2f(fmaf(s1[2 * j],     c, -mc));
                    s1[2 * j + 1] = exp2f(fmaf(s1[2 * j + 1], c, -mc));
                    sm[j] = (s0[2 * j] + s0[2 * j + 1]) + (s1[2 * j] + s1[2 * j + 1]);
                }
                float psum = ((sm[0] + sm[1]) + (sm[2] + sm[3])) +
                             ((sm[4] + sm[5]) + (sm[6] + sm[7]));
                {
                    u32x2 rr = __builtin_amdgcn_permlane32_swap(
                        __float_as_uint(psum), __float_as_uint(psum), false, false);
                    psum += __uint_as_float(hi ? rr[0] : rr[1]);
                }
                lsum += psum;
                // ---- P -> A-frags (cvt_pk + permlane32_swap) + PV ----
#pragma unroll
                for (int kvb = 0; kvb < 2; ++kvb) {
                    unsigned wd[8];
#pragma unroll
                    for (int j = 0; j < 8; ++j) {
                        const float plo = kvb ? s1[2 * j] : s0[2 * j];
                        const float phi = kvb ? s1[2 * j + 1] : s0[2 * j + 1];
                        wd[j] = cvtpk(plo, phi);
                    }
                    u32x2 r0 = __builtin_amdgcn_permlane32_swap(wd[0], wd[2], false, false);
                    u32x2 r1 = __builtin_amdgcn_permlane32_swap(wd[1], wd[3], false, false);
                    u32x2 r2 = __builtin_amdgcn_permlane32_swap(wd[4], wd[6], false, false);
                    u32x2 r3 = __builtin_amdgcn_permlane32_swap(wd[5], wd[7], false, false);
                    u32x4 fa, fb;
                    fa[0] = r0[0]; fa[1] = r1[0]; fa[2] = r0[1]; fa[3] = r1[1];
                    fb[0] = r2[0]; fb[1] = r3[0]; fb[2] = r2[1]; fb[3] = r3[1];
                    const bf16x8 pa = as_bf16x8(fa), pb = as_bf16x8(fb);
                    __builtin_amdgcn_s_setprio(1);
                    o0 = __builtin_amdgcn_mfma_f32_32x32x16_bf16(pa, as_bf16x8(vf[kvb * 4 + 0]), o0, 0, 0, 0);
                    o1 = __builtin_amdgcn_mfma_f32_32x32x16_bf16(pa, as_bf16x8(vf[kvb * 4 + 1]), o1, 0, 0, 0);
                    o0 = __builtin_amdgcn_mfma_f32_32x32x16_bf16(pb, as_bf16x8(vf[kvb * 4 + 2]), o0, 0, 0, 0);
                    o1 = __builtin_amdgcn_mfma_f32_32x32x16_bf16(pb, as_bf16x8(vf[kvb * 4 + 3]), o1, 0, 0, 0);
                    __builtin_amdgcn_s_setprio(0);
                }
            }
        }
        // ---- epilogue ----
        const float linv = 1.f / lsum;
#pragma unroll
        for (int r = 0; r < 16; ++r) {
            const int roff = (r & 3) + 8 * (r >> 2) + hi * 4;
            const float invq = __shfl(linv, roff);
            const size_t base = ((size_t)(bb * 2048 + q0w + roff)) * 1024 + hh * 64 + q;
            Y[base] = f2bf(o0[r] * invq);
            Y[base + 32] = f2bf(o1[r] * invq);
        }
    }
}

// ---------------------------------------------------------------------------
extern "C" void kernel_launch(void* const* d_in, const int* in_sizes, int n_in,
                              void* d_out, int out_size, void* d_ws, size_t ws_size,
                              hipStream_t stream) {
    const float* x = (const float*)d_in[0];
    const float* Wqkv = (const float*)d_in[1];
    const float* bqkv = (const float*)d_in[2];
    const float* Wproj = (const float*)d_in[3];
    const float* bproj = (const float*)d_in[4];
    float* out = (float*)d_out;
    char* ws = (char*)d_ws;

    u16* Wtq = (u16*)(ws + 0);            // 3072x1024 bf16
    u16* Wtp = (u16*)(ws + 6291456);      // 1024x1024 bf16
    u16* Qb  = (u16*)(ws + 8388608);      // [B,H,T,64] bf16 x3 (Q,K,V)
    u16* Vb  = (u16*)(ws + 41943040);
    u16* Vtb = (u16*)(ws + 58720256);     // [B,H,64,T] bf16 (alias with Xb)
    u16* Xb  = (u16*)(ws + 58720256);     // x in bf16; dead before tv_bf16
    u16* Yb  = Vb;                        // alias: V dead after transpose

    xcast<<<4096, 256, 0, stream>>>(x, Xb);
    tcast_f32<<<dim3(16, 48), 256, 0, stream>>>(Wqkv, Wtq, 1024, 3072);
    tcast_f32<<<dim3(16, 16), 256, 0, stream>>>(Wproj, Wtp, 1024, 1024);
    gemm_kernel<0><<<dim3(64, 24), 256, 0, stream>>>(
        Xb, Wtq, bqkv, (void*)Qb, 8192, 3072, 1024);
    tv_bf16<<<dim3(32, 64), 256, 0, stream>>>(Vb, Vtb);
    attn_kernel<<<dim3(4, 64), 512, 0, stream>>>(
        Qb, Qb + 8388608, Vtb, Yb);
    gemm_kernel<1><<<dim3(64, 8), 256, 0, stream>>>(
        Yb, Wtp, bproj, (void*)out, 8192, 1024, 1024);
}